// Round 1
// baseline (232.577 us; speedup 1.0000x reference)
//
#include <hip/hip_runtime.h>
#include <hip/hip_bf16.h>

#define S 2048
#define D 1024
#define NH 16
#define DH 64
#define M_TOT 4096  // B*S

typedef float f32x4 __attribute__((ext_vector_type(4)));
typedef __bf16 bf16x8 __attribute__((ext_vector_type(8)));

static __device__ __forceinline__ ushort f2bf(float f) {
    unsigned u = __float_as_uint(f);
    u += 0x7fffu + ((u >> 16) & 1u);   // RNE
    return (ushort)(u >> 16);
}

// ---------------- elementwise f32 -> bf16 ----------------
__global__ void k_convert(const float* __restrict__ src, ushort* __restrict__ dst, int n4) {
    int i = blockIdx.x * blockDim.x + threadIdx.x;
    int stride = gridDim.x * blockDim.x;
    for (int idx = i; idx < n4; idx += stride) {
        float4 v = ((const float4*)src)[idx];
        ushort4 o;
        o.x = f2bf(v.x); o.y = f2bf(v.y); o.z = f2bf(v.z); o.w = f2bf(v.w);
        ((ushort4*)dst)[idx] = o;
    }
}

// ---------------- W [K][N] f32 -> Wt [N][K] bf16 ----------------
__global__ void k_transposeW(const float* __restrict__ src, ushort* __restrict__ dst) {
    __shared__ float tile[32][33];
    int bn = blockIdx.x * 32;   // src col (n)
    int bk = blockIdx.y * 32;   // src row (k)
    int tx = threadIdx.x & 31, ty = threadIdx.x >> 5;  // 256 threads
    #pragma unroll
    for (int i = 0; i < 32; i += 8)
        tile[ty + i][tx] = src[(size_t)(bk + ty + i) * D + bn + tx];
    __syncthreads();
    #pragma unroll
    for (int i = 0; i < 32; i += 8)
        dst[(size_t)(bn + ty + i) * D + bk + tx] = f2bf(tile[tx][ty + i]);
}

// ---------------- V [BH][S][DH] -> Vt [BH][DH][S] (bf16) ----------------
__global__ void k_transposeV(const ushort* __restrict__ src, ushort* __restrict__ dst) {
    __shared__ ushort tile[32][33];
    int bh = blockIdx.z;
    const ushort* s = src + (size_t)bh * S * DH;
    ushort* d = dst + (size_t)bh * DH * S;
    int s0 = blockIdx.x * 32;
    int d0 = blockIdx.y * 32;
    int tx = threadIdx.x & 31, ty = threadIdx.x >> 5;
    #pragma unroll
    for (int i = 0; i < 32; i += 8)
        tile[ty + i][tx] = s[(size_t)(s0 + ty + i) * DH + d0 + tx];
    __syncthreads();
    #pragma unroll
    for (int i = 0; i < 32; i += 8)
        d[(size_t)(d0 + ty + i) * S + s0 + tx] = tile[tx][ty + i];
}

// ---------------- GEMM TN: A[4096][1024] bf16, Bt[1024][1024] bf16 (row n = K-vector) ----------------
// mode 0: bf16 out in head layout [B][NH][S][DH]
// mode 1: f32 out [4096][1024] + bias
__global__ __launch_bounds__(256, 2) void k_gemm_tn(
    const ushort* __restrict__ A, const ushort* __restrict__ Bt,
    void* __restrict__ Cout, const float* __restrict__ bias, int mode)
{
    __shared__ ushort As[128][40];
    __shared__ ushort Bs[128][40];
    int tid = threadIdx.x;
    int wave = tid >> 6, lane = tid & 63;
    int wm = (wave >> 1) * 64, wn = (wave & 1) * 64;
    int bm = blockIdx.x * 128, bn = blockIdx.y * 128;
    f32x4 acc[4][4] = {};

    int sr = tid >> 2;          // 0..63
    int sc = (tid & 3) * 8;     // 0,8,16,24
    const ushort* Ap = A + (size_t)(bm + sr) * D + sc;
    const ushort* Bp = Bt + (size_t)(bn + sr) * D + sc;

    int lr = lane & 15;
    int lk = (lane >> 4) * 8;

    for (int k0 = 0; k0 < D; k0 += 32) {
        int4 a0 = *(const int4*)(Ap);
        int4 a1 = *(const int4*)(Ap + 64 * D);
        int4 b0 = *(const int4*)(Bp);
        int4 b1 = *(const int4*)(Bp + 64 * D);
        Ap += 32; Bp += 32;
        __syncthreads();
        *(int4*)&As[sr][sc]      = a0;
        *(int4*)&As[sr + 64][sc] = a1;
        *(int4*)&Bs[sr][sc]      = b0;
        *(int4*)&Bs[sr + 64][sc] = b1;
        __syncthreads();
        bf16x8 af[4], bfr[4];
        #pragma unroll
        for (int m = 0; m < 4; ++m) af[m] = *(const bf16x8*)&As[wm + m * 16 + lr][lk];
        #pragma unroll
        for (int n = 0; n < 4; ++n) bfr[n] = *(const bf16x8*)&Bs[wn + n * 16 + lr][lk];
        #pragma unroll
        for (int m = 0; m < 4; ++m)
            #pragma unroll
            for (int n = 0; n < 4; ++n)
                acc[m][n] = __builtin_amdgcn_mfma_f32_16x16x32_bf16(af[m], bfr[n], acc[m][n], 0, 0, 0);
    }

    int rr = (lane >> 4) * 4;
    if (mode == 0) {
        ushort* O = (ushort*)Cout;
        #pragma unroll
        for (int m = 0; m < 4; ++m) {
            #pragma unroll
            for (int n = 0; n < 4; ++n) {
                int gn = bn + wn + n * 16 + lr;
                int h = gn >> 6, dd = gn & (DH - 1);
                #pragma unroll
                for (int r = 0; r < 4; ++r) {
                    int gm = bm + wm + m * 16 + rr + r;
                    int b = gm >> 11, ss = gm & (S - 1);
                    O[((size_t)(b * NH + h) * S + ss) * DH + dd] = f2bf(acc[m][n][r]);
                }
            }
        }
    } else {
        float* O = (float*)Cout;
        #pragma unroll
        for (int m = 0; m < 4; ++m) {
            #pragma unroll
            for (int n = 0; n < 4; ++n) {
                int gn = bn + wn + n * 16 + lr;
                float bv = bias[gn];
                #pragma unroll
                for (int r = 0; r < 4; ++r) {
                    int gm = bm + wm + m * 16 + rr + r;
                    O[(size_t)gm * D + gn] = acc[m][n][r] + bv;
                }
            }
        }
    }
}

// ---------------- flash attention, causal ----------------
// Qh,Kh: [BH][S][DH] bf16; Vt: [BH][DH][S] bf16; ctx: [B][S][D] bf16
__global__ __launch_bounds__(256, 2) void k_attn(
    const ushort* __restrict__ Qh, const ushort* __restrict__ Kh,
    const ushort* __restrict__ Vt, ushort* __restrict__ ctx)
{
    __shared__ ushort Ks[64][72];     // [kv][dh]
    __shared__ ushort Vs[64][72];     // [dh][kv]
    __shared__ ushort Ps[4][16][80];  // per-wave P [qrow][kv]
    int bh = blockIdx.y;
    int qb0 = blockIdx.x * 64;
    int wave = threadIdx.x >> 6, lane = threadIdx.x & 63;
    int q0 = qb0 + wave * 16;
    int lr = lane & 15;
    int lk = (lane >> 4) * 8;
    int rr = (lane >> 4) * 4;
    const ushort* Qp = Qh + (size_t)bh * S * DH;
    const ushort* Kp = Kh + (size_t)bh * S * DH;
    const ushort* Vp = Vt + (size_t)bh * DH * S;

    bf16x8 qf[2];
    #pragma unroll
    for (int c = 0; c < 2; ++c)
        qf[c] = *(const bf16x8*)&Qp[(size_t)(q0 + lr) * DH + c * 32 + lk];

    f32x4 acc[4] = {};
    float mrow[4], lrow[4];
    #pragma unroll
    for (int r = 0; r < 4; ++r) { mrow[r] = -1e30f; lrow[r] = 0.f; }

    int r0 = threadIdx.x >> 3;        // 0..31
    int c0 = (threadIdx.x & 7) * 8;   // 0..56

    int ntiles = qb0 / 64 + 1;
    for (int t = 0; t < ntiles; ++t) {
        int kv0 = t * 64;
        __syncthreads();
        *(int4*)&Ks[r0][c0]      = *(const int4*)&Kp[(size_t)(kv0 + r0) * DH + c0];
        *(int4*)&Ks[r0 + 32][c0] = *(const int4*)&Kp[(size_t)(kv0 + r0 + 32) * DH + c0];
        *(int4*)&Vs[r0][c0]      = *(const int4*)&Vp[(size_t)r0 * S + kv0 + c0];
        *(int4*)&Vs[r0 + 32][c0] = *(const int4*)&Vp[(size_t)(r0 + 32) * S + kv0 + c0];
        __syncthreads();

        f32x4 sc4[4] = {};
        #pragma unroll
        for (int nt = 0; nt < 4; ++nt)
            #pragma unroll
            for (int c = 0; c < 2; ++c) {
                bf16x8 kf = *(const bf16x8*)&Ks[nt * 16 + lr][c * 32 + lk];
                sc4[nt] = __builtin_amdgcn_mfma_f32_16x16x32_bf16(qf[c], kf, sc4[nt], 0, 0, 0);
            }

        float corr[4];
        #pragma unroll
        for (int r = 0; r < 4; ++r) {
            int qrow = q0 + rr + r;
            float mx = -1e30f;
            #pragma unroll
            for (int nt = 0; nt < 4; ++nt) {
                float v = sc4[nt][r] * 0.125f;
                int kvcol = kv0 + nt * 16 + lr;
                v = (kvcol > qrow) ? -1e30f : v;
                sc4[nt][r] = v;
                mx = fmaxf(mx, v);
            }
            #pragma unroll
            for (int off = 1; off < 16; off <<= 1)
                mx = fmaxf(mx, __shfl_xor(mx, off));
            float mnew = fmaxf(mrow[r], mx);
            float cr = __expf(mrow[r] - mnew);
            corr[r] = cr;
            float ssum = 0.f;
            #pragma unroll
            for (int nt = 0; nt < 4; ++nt) {
                float p = __expf(sc4[nt][r] - mnew);
                sc4[nt][r] = p;
                ssum += p;
            }
            #pragma unroll
            for (int off = 1; off < 16; off <<= 1)
                ssum += __shfl_xor(ssum, off);
            lrow[r] = lrow[r] * cr + ssum;
            mrow[r] = mnew;
        }
        #pragma unroll
        for (int dt = 0; dt < 4; ++dt)
            #pragma unroll
            for (int r = 0; r < 4; ++r)
                acc[dt][r] *= corr[r];

        #pragma unroll
        for (int nt = 0; nt < 4; ++nt)
            #pragma unroll
            for (int r = 0; r < 4; ++r)
                Ps[wave][rr + r][nt * 16 + lr] = f2bf(sc4[nt][r]);

        #pragma unroll
        for (int kc = 0; kc < 2; ++kc) {
            bf16x8 pf = *(const bf16x8*)&Ps[wave][lr][kc * 32 + lk];
            #pragma unroll
            for (int dt = 0; dt < 4; ++dt) {
                bf16x8 vf = *(const bf16x8*)&Vs[dt * 16 + lr][kc * 32 + lk];
                acc[dt] = __builtin_amdgcn_mfma_f32_16x16x32_bf16(pf, vf, acc[dt], 0, 0, 0);
            }
        }
    }

    int b = bh >> 4, h = bh & (NH - 1);
    #pragma unroll
    for (int dt = 0; dt < 4; ++dt)
        #pragma unroll
        for (int r = 0; r < 4; ++r) {
            int qrow = q0 + rr + r;
            float o = acc[dt][r] / lrow[r];
            ctx[((size_t)(b * S + qrow)) * D + h * DH + dt * 16 + lr] = f2bf(o);
        }
}

extern "C" void kernel_launch(void* const* d_in, const int* in_sizes, int n_in,
                              void* d_out, int out_size, void* d_ws, size_t ws_size,
                              hipStream_t stream) {
    const float* X   = (const float*)d_in[0];
    const float* W_q = (const float*)d_in[1];
    const float* W_k = (const float*)d_in[2];
    const float* W_v = (const float*)d_in[3];
    const float* W_o = (const float*)d_in[4];
    const float* b_o = (const float*)d_in[5];
    float* out = (float*)d_out;

    ushort* Xb  = (ushort*)d_ws;                   // [4096][1024]
    ushort* Wqt = Xb  + (size_t)M_TOT * D;         // [1024][1024] each (transposed)
    ushort* Wkt = Wqt + (size_t)D * D;
    ushort* Wvt = Wkt + (size_t)D * D;
    ushort* Wot = Wvt + (size_t)D * D;
    ushort* Qh  = Wot + (size_t)D * D;             // [32][2048][64]
    ushort* Kh  = Qh  + (size_t)M_TOT * D;
    ushort* Vh  = Kh  + (size_t)M_TOT * D;
    ushort* Vtr = Vh  + (size_t)M_TOT * D;         // [32][64][2048]
    ushort* Ctx = Vtr + (size_t)M_TOT * D;         // [4096][1024]

    k_convert<<<dim3(2048), dim3(256), 0, stream>>>(X, Xb, M_TOT * D / 4);

    dim3 tg(32, 32);
    k_transposeW<<<tg, dim3(256), 0, stream>>>(W_q, Wqt);
    k_transposeW<<<tg, dim3(256), 0, stream>>>(W_k, Wkt);
    k_transposeW<<<tg, dim3(256), 0, stream>>>(W_v, Wvt);
    k_transposeW<<<tg, dim3(256), 0, stream>>>(W_o, Wot);

    dim3 gg(32, 8);
    k_gemm_tn<<<gg, dim3(256), 0, stream>>>(Xb, Wqt, Qh, nullptr, 0);
    k_gemm_tn<<<gg, dim3(256), 0, stream>>>(Xb, Wkt, Kh, nullptr, 0);
    k_gemm_tn<<<gg, dim3(256), 0, stream>>>(Xb, Wvt, Vh, nullptr, 0);

    k_transposeV<<<dim3(64, 2, 32), dim3(256), 0, stream>>>(Vh, Vtr);

    k_attn<<<dim3(32, 32), dim3(256), 0, stream>>>(Qh, Kh, Vtr, Ctx);

    k_gemm_tn<<<gg, dim3(256), 0, stream>>>(Ctx, Wot, out, b_o, 1);
}

// Round 2
// 166.996 us; speedup vs baseline: 1.3927x; 1.3927x over previous
//
#include <hip/hip_runtime.h>
#include <hip/hip_bf16.h>

#define S 2048
#define D 1024
#define NH 16
#define DH 64
#define M_TOT 4096  // B*S

typedef float f32x4 __attribute__((ext_vector_type(4)));
typedef float f32x16 __attribute__((ext_vector_type(16)));
typedef __bf16 bf16x8 __attribute__((ext_vector_type(8)));

static __device__ __forceinline__ ushort f2bf(float f) {
    unsigned u = __float_as_uint(f);
    u += 0x7fffu + ((u >> 16) & 1u);   // RNE
    return (ushort)(u >> 16);
}

static __device__ __forceinline__ int cvtpk_bf16(float lo, float hi) {
    int r;
    asm("v_cvt_pk_bf16_f32 %0, %1, %2" : "=v"(r) : "v"(lo), "v"(hi));
    return r;
}

static __device__ __forceinline__ void plswap(int& a, int& b) {
    asm("v_permlane32_swap_b32 %0, %1" : "+v"(a), "+v"(b));
}

static __device__ __forceinline__ void gload16(const ushort* g, ushort* l) {
    __builtin_amdgcn_global_load_lds(
        (const __attribute__((address_space(1))) void*)g,
        (__attribute__((address_space(3))) void*)l, 16, 0, 0);
}

// ---------------- elementwise f32 -> bf16 ----------------
__global__ void k_convert(const float* __restrict__ src, ushort* __restrict__ dst, int n4) {
    int i = blockIdx.x * blockDim.x + threadIdx.x;
    int stride = gridDim.x * blockDim.x;
    for (int idx = i; idx < n4; idx += stride) {
        float4 v = ((const float4*)src)[idx];
        ushort4 o;
        o.x = f2bf(v.x); o.y = f2bf(v.y); o.z = f2bf(v.z); o.w = f2bf(v.w);
        ((ushort4*)dst)[idx] = o;
    }
}

// ---------------- W [K][N] f32 -> Wt [N][K] bf16 ----------------
__global__ void k_transposeW(const float* __restrict__ src, ushort* __restrict__ dst) {
    __shared__ float tile[32][33];
    int bn = blockIdx.x * 32;
    int bk = blockIdx.y * 32;
    int tx = threadIdx.x & 31, ty = threadIdx.x >> 5;
    #pragma unroll
    for (int i = 0; i < 32; i += 8)
        tile[ty + i][tx] = src[(size_t)(bk + ty + i) * D + bn + tx];
    __syncthreads();
    #pragma unroll
    for (int i = 0; i < 32; i += 8)
        dst[(size_t)(bn + ty + i) * D + bk + tx] = f2bf(tile[tx][ty + i]);
}

// ---------------- V [BH][S][DH] -> Vt [BH][DH][S] (bf16) ----------------
__global__ void k_transposeV(const ushort* __restrict__ src, ushort* __restrict__ dst) {
    __shared__ ushort tile[32][33];
    int bh = blockIdx.z;
    const ushort* s = src + (size_t)bh * S * DH;
    ushort* d = dst + (size_t)bh * DH * S;
    int s0 = blockIdx.x * 32;
    int d0 = blockIdx.y * 32;
    int tx = threadIdx.x & 31, ty = threadIdx.x >> 5;
    #pragma unroll
    for (int i = 0; i < 32; i += 8)
        tile[ty + i][tx] = s[(size_t)(s0 + ty + i) * DH + d0 + tx];
    __syncthreads();
    #pragma unroll
    for (int i = 0; i < 32; i += 8)
        d[(size_t)(d0 + ty + i) * S + s0 + tx] = tile[tx][ty + i];
}

// ---------------- GEMM TN ----------------
__global__ __launch_bounds__(256, 2) void k_gemm_tn(
    const ushort* __restrict__ A, const ushort* __restrict__ Bt,
    void* __restrict__ Cout, const float* __restrict__ bias, int mode)
{
    __shared__ ushort As[128][40];
    __shared__ ushort Bs[128][40];
    int tid = threadIdx.x;
    int wave = tid >> 6, lane = tid & 63;
    int wm = (wave >> 1) * 64, wn = (wave & 1) * 64;
    int bm = blockIdx.x * 128, bn = blockIdx.y * 128;
    f32x4 acc[4][4] = {};

    int sr = tid >> 2;
    int sc = (tid & 3) * 8;
    const ushort* Ap = A + (size_t)(bm + sr) * D + sc;
    const ushort* Bp = Bt + (size_t)(bn + sr) * D + sc;

    int lr = lane & 15;
    int lk = (lane >> 4) * 8;

    for (int k0 = 0; k0 < D; k0 += 32) {
        int4 a0 = *(const int4*)(Ap);
        int4 a1 = *(const int4*)(Ap + 64 * D);
        int4 b0 = *(const int4*)(Bp);
        int4 b1 = *(const int4*)(Bp + 64 * D);
        Ap += 32; Bp += 32;
        __syncthreads();
        *(int4*)&As[sr][sc]      = a0;
        *(int4*)&As[sr + 64][sc] = a1;
        *(int4*)&Bs[sr][sc]      = b0;
        *(int4*)&Bs[sr + 64][sc] = b1;
        __syncthreads();
        bf16x8 af[4], bfr[4];
        #pragma unroll
        for (int m = 0; m < 4; ++m) af[m] = *(const bf16x8*)&As[wm + m * 16 + lr][lk];
        #pragma unroll
        for (int n = 0; n < 4; ++n) bfr[n] = *(const bf16x8*)&Bs[wn + n * 16 + lr][lk];
        #pragma unroll
        for (int m = 0; m < 4; ++m)
            #pragma unroll
            for (int n = 0; n < 4; ++n)
                acc[m][n] = __builtin_amdgcn_mfma_f32_16x16x32_bf16(af[m], bfr[n], acc[m][n], 0, 0, 0);
    }

    int rr = (lane >> 4) * 4;
    if (mode == 0) {
        ushort* O = (ushort*)Cout;
        #pragma unroll
        for (int m = 0; m < 4; ++m) {
            #pragma unroll
            for (int n = 0; n < 4; ++n) {
                int gn = bn + wn + n * 16 + lr;
                int h = gn >> 6, dd = gn & (DH - 1);
                #pragma unroll
                for (int r = 0; r < 4; ++r) {
                    int gm = bm + wm + m * 16 + rr + r;
                    int b = gm >> 11, ss = gm & (S - 1);
                    O[((size_t)(b * NH + h) * S + ss) * DH + dd] = f2bf(acc[m][n][r]);
                }
            }
        }
    } else {
        float* O = (float*)Cout;
        #pragma unroll
        for (int m = 0; m < 4; ++m) {
            #pragma unroll
            for (int n = 0; n < 4; ++n) {
                int gn = bn + wn + n * 16 + lr;
                float bv = bias[gn];
                #pragma unroll
                for (int r = 0; r < 4; ++r) {
                    int gm = bm + wm + m * 16 + rr + r;
                    O[(size_t)gm * D + gn] = acc[m][n][r] + bv;
                }
            }
        }
    }
}

// ---------------- flash attention, causal, 32x32 swapped-QK^T ----------------
// Qh,Kh: [BH][S][DH] bf16; Vt: [BH][DH][S] bf16; ctx: [B][S][D] bf16
__global__ __launch_bounds__(256, 2) void k_attn(
    const ushort* __restrict__ Qh, const ushort* __restrict__ Kh,
    const ushort* __restrict__ Vt, ushort* __restrict__ ctx)
{
    __shared__ ushort Ks[2 * 64 * 64];   // double-buffered, XOR-swizzled 16B chunks
    __shared__ ushort Vs[2 * 64 * 64];

    int bid = blockIdx.x;
    int bh = bid & 31;
    int qb = (bid < 256) ? (bid >> 5) : (15 - ((bid - 256) >> 5));  // causal pairing
    int wave = threadIdx.x >> 6, lane = threadIdx.x & 63;
    int lo5 = lane & 31, hi = lane >> 5;
    int q0w = qb * 128 + wave * 32;
    int qg = q0w + lo5;
    int tid = threadIdx.x;

    const ushort* Qp = Qh + (size_t)bh * S * DH;
    const ushort* Kp = Kh + (size_t)bh * S * DH;
    const ushort* Vp = Vt + (size_t)bh * DH * S;

    // Q as B-fragments: col=q (lane&31), k = ks*16 + hi*8 + j
    bf16x8 qf[4];
    #pragma unroll
    for (int ks = 0; ks < 4; ++ks)
        qf[ks] = *(const bf16x8*)&Qp[(size_t)qg * DH + ks * 16 + hi * 8];

    f32x16 oacc[2] = {};
    float m = -1e30f, l = 0.f;

    int ntiles = 2 * qb + 2;

    // prologue: stage tile 0 into buffer 0
    {
        int p0 = tid, r0 = p0 >> 3, c0 = p0 & 7;
        gload16(Kp + (size_t)r0 * DH + ((c0 ^ (r0 & 7)) << 3), &Ks[p0 << 3]);
        gload16(Vp + (size_t)r0 * S + ((c0 ^ (r0 & 7)) << 3), &Vs[p0 << 3]);
        int p1 = tid + 256, r1 = p1 >> 3, c1 = p1 & 7;
        gload16(Kp + (size_t)r1 * DH + ((c1 ^ (r1 & 7)) << 3), &Ks[p1 << 3]);
        gload16(Vp + (size_t)r1 * S + ((c1 ^ (r1 & 7)) << 3), &Vs[p1 << 3]);
    }
    asm volatile("s_waitcnt vmcnt(0)" ::: "memory");
    __syncthreads();

    int cur = 0;
    for (int t = 0; t < ntiles; ++t) {
        int kv0 = t * 64;
        // stage next tile into other buffer (overlaps with compute below)
        if (t + 1 < ntiles) {
            int kvn = kv0 + 64;
            ushort* KsB = &Ks[(cur ^ 1) * 4096];
            ushort* VsB = &Vs[(cur ^ 1) * 4096];
            int p0 = tid, r0 = p0 >> 3, c0 = p0 & 7;
            gload16(Kp + (size_t)(kvn + r0) * DH + ((c0 ^ (r0 & 7)) << 3), KsB + (p0 << 3));
            gload16(Vp + (size_t)r0 * S + kvn + ((c0 ^ (r0 & 7)) << 3), VsB + (p0 << 3));
            int p1 = tid + 256, r1 = p1 >> 3, c1 = p1 & 7;
            gload16(Kp + (size_t)(kvn + r1) * DH + ((c1 ^ (r1 & 7)) << 3), KsB + (p1 << 3));
            gload16(Vp + (size_t)r1 * S + kvn + ((c1 ^ (r1 & 7)) << 3), VsB + (p1 << 3));
        }

        if (kv0 <= q0w + 31) {
            const ushort* KsC = &Ks[cur * 4096];
            const ushort* VsC = &Vs[cur * 4096];
            int rx = lo5 & 7;

            // QK^T swapped: S^T[kv][q] = mfma(A=K rows, B=Q cols)
            f32x16 sc[2];
            sc[0] = (f32x16)(0.f);
            sc[1] = (f32x16)(0.f);
            #pragma unroll
            for (int ks = 0; ks < 4; ++ks) {
                bf16x8 kf0 = *(const bf16x8*)&KsC[lo5 * 64 + (((2 * ks + hi) ^ rx) << 3)];
                sc[0] = __builtin_amdgcn_mfma_f32_32x32x16_bf16(kf0, qf[ks], sc[0], 0, 0, 0);
                bf16x8 kf1 = *(const bf16x8*)&KsC[(32 + lo5) * 64 + (((2 * ks + hi) ^ rx) << 3)];
                sc[1] = __builtin_amdgcn_mfma_f32_32x32x16_bf16(kf1, qf[ks], sc[1], 0, 0, 0);
            }

            // softmax in log2 domain; lane owns q-col = qg, kv rows crow(r,hi)+32*sub
            const float SC2 = 0.18033688011112042f;  // 0.125 * log2(e)
            float mx = -1e30f;
            if (kv0 + 63 > q0w) {
                #pragma unroll
                for (int sub = 0; sub < 2; ++sub)
                    #pragma unroll
                    for (int r = 0; r < 16; ++r) {
                        int kvg = kv0 + 32 * sub + ((r & 3) + 8 * (r >> 2) + 4 * hi);
                        float v = sc[sub][r] * SC2;
                        v = (kvg > qg) ? -1e30f : v;
                        sc[sub][r] = v;
                        mx = fmaxf(mx, v);
                    }
            } else {
                #pragma unroll
                for (int sub = 0; sub < 2; ++sub)
                    #pragma unroll
                    for (int r = 0; r < 16; ++r) {
                        float v = sc[sub][r] * SC2;
                        sc[sub][r] = v;
                        mx = fmaxf(mx, v);
                    }
            }
            mx = fmaxf(mx, __shfl_xor(mx, 32));
            float mnew = fmaxf(m, mx);
            float corr = exp2f(m - mnew);
            m = mnew;
            float sum = 0.f;
            #pragma unroll
            for (int sub = 0; sub < 2; ++sub)
                #pragma unroll
                for (int r = 0; r < 16; ++r) {
                    float p = exp2f(sc[sub][r] - mnew);
                    sc[sub][r] = p;
                    sum += p;
                }
            sum += __shfl_xor(sum, 32);
            l = l * corr + sum;
            #pragma unroll
            for (int sub = 0; sub < 2; ++sub)
                #pragma unroll
                for (int r = 0; r < 16; ++r)
                    oacc[sub][r] *= corr;

            // repack P -> bf16 B-fragments (col=q, k=kv) via cvt_pk + permlane32_swap
            bf16x8 pb[4];
            #pragma unroll
            for (int sub = 0; sub < 2; ++sub) {
                int a0 = cvtpk_bf16(sc[sub][0], sc[sub][1]);
                int b0 = cvtpk_bf16(sc[sub][4], sc[sub][5]);
                plswap(a0, b0);
                int a1 = cvtpk_bf16(sc[sub][2], sc[sub][3]);
                int b1 = cvtpk_bf16(sc[sub][6], sc[sub][7]);
                plswap(a1, b1);
                int4 w0; w0.x = a0; w0.y = a1; w0.z = b0; w0.w = b1;
                pb[2 * sub] = *(bf16x8*)&w0;
                int a2 = cvtpk_bf16(sc[sub][8], sc[sub][9]);
                int b2 = cvtpk_bf16(sc[sub][12], sc[sub][13]);
                plswap(a2, b2);
                int a3 = cvtpk_bf16(sc[sub][10], sc[sub][11]);
                int b3 = cvtpk_bf16(sc[sub][14], sc[sub][15]);
                plswap(a3, b3);
                int4 w1; w1.x = a2; w1.y = a3; w1.z = b2; w1.w = b3;
                pb[2 * sub + 1] = *(bf16x8*)&w1;
            }

            // PV: O^T[dh][q] += mfma(A = V^T rows (dh), B = P^T cols (q))
            #pragma unroll
            for (int ks = 0; ks < 4; ++ks) {
                bf16x8 vf0 = *(const bf16x8*)&VsC[lo5 * 64 + (((2 * ks + hi) ^ rx) << 3)];
                oacc[0] = __builtin_amdgcn_mfma_f32_32x32x16_bf16(vf0, pb[ks], oacc[0], 0, 0, 0);
                bf16x8 vf1 = *(const bf16x8*)&VsC[(32 + lo5) * 64 + (((2 * ks + hi) ^ rx) << 3)];
                oacc[1] = __builtin_amdgcn_mfma_f32_32x32x16_bf16(vf1, pb[ks], oacc[1], 0, 0, 0);
            }
        }

        asm volatile("s_waitcnt vmcnt(0)" ::: "memory");
        __syncthreads();
        cur ^= 1;
    }

    // epilogue: lane holds O^T[dh][qg]; normalize and scatter (4B packed pairs)
    float inv = 1.0f / l;
    int b = bh >> 4, h = bh & (NH - 1);
    ushort* cp = ctx + (size_t)(b * S + qg) * D + h * DH;
    #pragma unroll
    for (int sub = 0; sub < 2; ++sub)
        #pragma unroll
        for (int i = 0; i < 8; ++i) {
            int dh = ((2 * i) & 3) + 8 * ((2 * i) >> 2) + 4 * hi + 32 * sub;
            int w = cvtpk_bf16(oacc[sub][2 * i] * inv, oacc[sub][2 * i + 1] * inv);
            *(int*)&cp[dh] = w;
        }
}

extern "C" void kernel_launch(void* const* d_in, const int* in_sizes, int n_in,
                              void* d_out, int out_size, void* d_ws, size_t ws_size,
                              hipStream_t stream) {
    const float* X   = (const float*)d_in[0];
    const float* W_q = (const float*)d_in[1];
    const float* W_k = (const float*)d_in[2];
    const float* W_v = (const float*)d_in[3];
    const float* W_o = (const float*)d_in[4];
    const float* b_o = (const float*)d_in[5];
    float* out = (float*)d_out;

    ushort* Xb  = (ushort*)d_ws;
    ushort* Wqt = Xb  + (size_t)M_TOT * D;
    ushort* Wkt = Wqt + (size_t)D * D;
    ushort* Wvt = Wkt + (size_t)D * D;
    ushort* Wot = Wvt + (size_t)D * D;
    ushort* Qh  = Wot + (size_t)D * D;
    ushort* Kh  = Qh  + (size_t)M_TOT * D;
    ushort* Vh  = Kh  + (size_t)M_TOT * D;
    ushort* Vtr = Vh  + (size_t)M_TOT * D;
    ushort* Ctx = Vtr + (size_t)M_TOT * D;

    k_convert<<<dim3(2048), dim3(256), 0, stream>>>(X, Xb, M_TOT * D / 4);

    dim3 tg(32, 32);
    k_transposeW<<<tg, dim3(256), 0, stream>>>(W_q, Wqt);
    k_transposeW<<<tg, dim3(256), 0, stream>>>(W_k, Wkt);
    k_transposeW<<<tg, dim3(256), 0, stream>>>(W_v, Wvt);
    k_transposeW<<<tg, dim3(256), 0, stream>>>(W_o, Wot);

    dim3 gg(32, 8);
    k_gemm_tn<<<gg, dim3(256), 0, stream>>>(Xb, Wqt, Qh, nullptr, 0);
    k_gemm_tn<<<gg, dim3(256), 0, stream>>>(Xb, Wkt, Kh, nullptr, 0);
    k_gemm_tn<<<gg, dim3(256), 0, stream>>>(Xb, Wvt, Vh, nullptr, 0);

    k_transposeV<<<dim3(64, 2, 32), dim3(256), 0, stream>>>(Vh, Vtr);

    k_attn<<<dim3(512), dim3(256), 0, stream>>>(Qh, Kh, Vtr, Ctx);

    k_gemm_tn<<<gg, dim3(256), 0, stream>>>(Ctx, Wot, out, b_o, 1);
}

// Round 3
// 134.354 us; speedup vs baseline: 1.7311x; 1.2430x over previous
//
#include <hip/hip_runtime.h>
#include <hip/hip_bf16.h>

#define S 2048
#define D 1024
#define NH 16
#define DH 64
#define M_TOT 4096  // B*S

typedef float f32x4 __attribute__((ext_vector_type(4)));
typedef float f32x16 __attribute__((ext_vector_type(16)));
typedef __bf16 bf16x8 __attribute__((ext_vector_type(8)));

static __device__ __forceinline__ ushort f2bf(float f) {
    unsigned u = __float_as_uint(f);
    u += 0x7fffu + ((u >> 16) & 1u);   // RNE
    return (ushort)(u >> 16);
}

static __device__ __forceinline__ int cvtpk_bf16(float lo, float hi) {
    int r;
    asm("v_cvt_pk_bf16_f32 %0, %1, %2" : "=v"(r) : "v"(lo), "v"(hi));
    return r;
}

static __device__ __forceinline__ void plswap(int& a, int& b) {
    asm("v_permlane32_swap_b32 %0, %1" : "+v"(a), "+v"(b));
}

static __device__ __forceinline__ void gload16(const ushort* g, ushort* l) {
    __builtin_amdgcn_global_load_lds(
        (const __attribute__((address_space(1))) void*)g,
        (__attribute__((address_space(3))) void*)l, 16, 0, 0);
}

// ---------------- elementwise f32 -> bf16 ----------------
__global__ void k_convert(const float* __restrict__ src, ushort* __restrict__ dst, int n4) {
    int i = blockIdx.x * blockDim.x + threadIdx.x;
    int stride = gridDim.x * blockDim.x;
    for (int idx = i; idx < n4; idx += stride) {
        float4 v = ((const float4*)src)[idx];
        ushort4 o;
        o.x = f2bf(v.x); o.y = f2bf(v.y); o.z = f2bf(v.z); o.w = f2bf(v.w);
        ((ushort4*)dst)[idx] = o;
    }
}

// ---------------- W [K][N] f32 -> Wt [zoff+N][K] bf16 ----------------
__global__ void k_transposeW(const float* __restrict__ w0, const float* __restrict__ w1,
                             const float* __restrict__ w2, ushort* __restrict__ dst) {
    __shared__ float tile[32][33];
    int z = blockIdx.z;
    const float* src = (z == 0) ? w0 : (z == 1) ? w1 : w2;
    int zoff = z * 1024;
    int bn = blockIdx.x * 32;
    int bk = blockIdx.y * 32;
    int tx = threadIdx.x & 31, ty = threadIdx.x >> 5;
    #pragma unroll
    for (int i = 0; i < 32; i += 8)
        tile[ty + i][tx] = src[(size_t)(bk + ty + i) * D + bn + tx];
    __syncthreads();
    #pragma unroll
    for (int i = 0; i < 32; i += 8)
        dst[(size_t)(zoff + bn + ty + i) * D + bk + tx] = f2bf(tile[tx][ty + i]);
}

// ---------------- V [BH][S][DH] -> Vt [BH][DH][S] (bf16) ----------------
__global__ void k_transposeV(const ushort* __restrict__ src, ushort* __restrict__ dst) {
    __shared__ ushort tile[32][33];
    int bh = blockIdx.z;
    const ushort* s = src + (size_t)bh * S * DH;
    ushort* d = dst + (size_t)bh * DH * S;
    int s0 = blockIdx.x * 32;
    int d0 = blockIdx.y * 32;
    int tx = threadIdx.x & 31, ty = threadIdx.x >> 5;
    #pragma unroll
    for (int i = 0; i < 32; i += 8)
        tile[ty + i][tx] = s[(size_t)(s0 + ty + i) * DH + d0 + tx];
    __syncthreads();
    #pragma unroll
    for (int i = 0; i < 32; i += 8)
        d[(size_t)(d0 + ty + i) * S + s0 + tx] = tile[tx][ty + i];
}

// ---------------- GEMM TN, m97-style: global_load_lds staging ----------------
// MF: wave rows = MF*16, BM = MF*32. BN=128, BK=32.
// mode 0: bf16 out scattered to Qd/Kd/Vd head layout [B][NH][S][DH] (N=3072)
// mode 1: f32 out [4096][1024] + bias (N=1024)
template<int MF>
__global__ __launch_bounds__(256) void k_gemm(
    const ushort* __restrict__ A, const ushort* __restrict__ Bt,
    ushort* __restrict__ Qd, ushort* __restrict__ Kd, ushort* __restrict__ Vd,
    float* __restrict__ Od, const float* __restrict__ bias, int mode)
{
    constexpr int BM = MF * 32;
    __shared__ ushort As[BM * 32];
    __shared__ ushort Bs[128 * 32];
    int tid = threadIdx.x, wave = tid >> 6, lane = tid & 63;
    int wm = (wave >> 1) * (MF * 16), wn = (wave & 1) * 64;
    int bm = blockIdx.x * BM, bn0 = blockIdx.y * 128;
    int lr = lane & 15, lk = (lane >> 4) * 8;
    f32x4 acc[MF][4] = {};

    const ushort* Ap0 = A + (size_t)(bm + (tid >> 2)) * D + (tid & 3) * 8;
    const ushort* Ap1 = A + (size_t)(bm + ((tid + 256) >> 2)) * D + (tid & 3) * 8;
    const ushort* Bp0 = Bt + (size_t)(bn0 + (tid >> 2)) * D + (tid & 3) * 8;
    const ushort* Bp1 = Bt + (size_t)(bn0 + ((tid + 256) >> 2)) * D + (tid & 3) * 8;
    ushort* la0 = As + tid * 8;
    ushort* la1 = As + (tid + 256) * 8;
    ushort* lb0 = Bs + tid * 8;
    ushort* lb1 = Bs + (tid + 256) * 8;

    for (int k0 = 0; k0 < D; k0 += 32) {
        __syncthreads();   // prior iteration's ds_reads done before overwrite
        gload16(Ap0, la0);
        if constexpr (MF == 4) gload16(Ap1, la1);
        gload16(Bp0, lb0);
        gload16(Bp1, lb1);
        Ap0 += 32; Bp0 += 32; Bp1 += 32;
        if constexpr (MF == 4) Ap1 += 32;
        asm volatile("s_waitcnt vmcnt(0)" ::: "memory");
        __syncthreads();
        bf16x8 af[MF], bfr[4];
        #pragma unroll
        for (int m = 0; m < MF; ++m) af[m] = *(const bf16x8*)&As[(wm + m * 16 + lr) * 32 + lk];
        #pragma unroll
        for (int n = 0; n < 4; ++n) bfr[n] = *(const bf16x8*)&Bs[(wn + n * 16 + lr) * 32 + lk];
        #pragma unroll
        for (int m = 0; m < MF; ++m)
            #pragma unroll
            for (int n = 0; n < 4; ++n)
                acc[m][n] = __builtin_amdgcn_mfma_f32_16x16x32_bf16(af[m], bfr[n], acc[m][n], 0, 0, 0);
    }

    int rr = (lane >> 4) * 4;
    if (mode == 0) {
        ushort* Dst = (blockIdx.y < 8) ? Qd : ((blockIdx.y < 16) ? Kd : Vd);
        int bnc = (blockIdx.y & 7) * 128;
        #pragma unroll
        for (int m = 0; m < MF; ++m) {
            #pragma unroll
            for (int n = 0; n < 4; ++n) {
                int gn = bnc + wn + n * 16 + lr;
                int h = gn >> 6, dd = gn & (DH - 1);
                #pragma unroll
                for (int r = 0; r < 4; ++r) {
                    int gm = bm + wm + m * 16 + rr + r;
                    int b = gm >> 11, ss = gm & (S - 1);
                    Dst[((size_t)(b * NH + h) * S + ss) * DH + dd] = f2bf(acc[m][n][r]);
                }
            }
        }
    } else {
        #pragma unroll
        for (int m = 0; m < MF; ++m) {
            #pragma unroll
            for (int n = 0; n < 4; ++n) {
                int gn = bn0 + wn + n * 16 + lr;
                float bv = bias[gn];
                #pragma unroll
                for (int r = 0; r < 4; ++r) {
                    int gm = bm + wm + m * 16 + rr + r;
                    Od[(size_t)gm * D + gn] = acc[m][n][r] + bv;
                }
            }
        }
    }
}

// ---------------- flash attention, causal, balanced pair + split-kv waves ----------------
// Block: 64 q-rows (2 qsubs x 32), 4 waves: wave = (qsub, kpar); kv tiles split
// even/odd across kpar, merged per pair at the end of each q-tile.
// Processes q-tile 31-j then j  => uniform 33 tiles per block.
__global__ __launch_bounds__(256) void k_attn(
    const ushort* __restrict__ Qh, const ushort* __restrict__ Kh,
    const ushort* __restrict__ Vt, ushort* __restrict__ ctx)
{
    __shared__ ushort Ks[2][2][64 * 64];   // [dbuf][kpar][kv][dh] (16B-chunk XOR swizzled)
    __shared__ ushort Vs[2][2][64 * 64];   // [dbuf][kpar][dh][kv]

    int bid = blockIdx.x;
    int bh = bid & 31;
    int j = bid >> 5;                       // 0..15
    int tid = threadIdx.x;
    int wave = tid >> 6, lane = tid & 63;
    int lo5 = lane & 31, hi = lane >> 5;
    int qs = wave >> 1, kp = wave & 1;
    int rx = lo5 & 7;
    const ushort* Qp = Qh + (size_t)bh * S * DH;
    const ushort* Kp = Kh + (size_t)bh * S * DH;
    const ushort* Vp = Vt + (size_t)bh * DH * S;
    int b = bh >> 4, h = bh & (NH - 1);

    auto stage = [&](int t, int buf) {
        int kv0 = t * 64;
        ushort* kd = &Ks[buf][t & 1][0];
        ushort* vd = &Vs[buf][t & 1][0];
        int c0 = tid, c1 = tid + 256;
        int r0 = c0 >> 3, cc0 = c0 & 7, r1 = c1 >> 3, cc1 = c1 & 7;
        gload16(Kp + (size_t)(kv0 + r0) * DH + ((cc0 ^ (r0 & 7)) << 3), kd + c0 * 8);
        gload16(Kp + (size_t)(kv0 + r1) * DH + ((cc1 ^ (r1 & 7)) << 3), kd + c1 * 8);
        gload16(Vp + (size_t)r0 * S + kv0 + ((cc0 ^ (r0 & 7)) << 3), vd + c0 * 8);
        gload16(Vp + (size_t)r1 * S + kv0 + ((cc1 ^ (r1 & 7)) << 3), vd + c1 * 8);
    };

    #pragma unroll 1
    for (int half = 0; half < 2; ++half) {
        int qt = half ? j : (31 - j);       // heavy tile first
        int q0 = qt * 64;
        int q0w = q0 + qs * 32;
        int qg = q0w + lo5;
        int nt = qt + 1;
        int P = (nt + 1) >> 1;

        bf16x8 qf[4];
        #pragma unroll
        for (int ks = 0; ks < 4; ++ks)
            qf[ks] = *(const bf16x8*)&Qp[(size_t)qg * DH + ks * 16 + hi * 8];

        f32x16 oacc[2] = {};
        float m = -1e28f, l = 0.f;

        // prologue: stage tiles 0 (and 1) into buf 0
        stage(0, 0);
        if (1 < nt) stage(1, 0);
        asm volatile("s_waitcnt vmcnt(0)" ::: "memory");
        __syncthreads();

        int cur = 0;
        #pragma unroll 1
        for (int i = 0; i < P; ++i) {
            if (i + 1 < P) {
                stage(2 * i + 2, cur ^ 1);
                if (2 * i + 3 < nt) stage(2 * i + 3, cur ^ 1);
            }
            int t = 2 * i + kp;
            if (t < nt) {
                int kv0 = t * 64;
                const ushort* KsC = &Ks[cur][kp][0];
                const ushort* VsC = &Vs[cur][kp][0];

                f32x16 sc[2];
                sc[0] = (f32x16)(0.f);
                sc[1] = (f32x16)(0.f);
                #pragma unroll
                for (int ks = 0; ks < 4; ++ks) {
                    bf16x8 kf0 = *(const bf16x8*)&KsC[lo5 * 64 + (((2 * ks + hi) ^ rx) << 3)];
                    sc[0] = __builtin_amdgcn_mfma_f32_32x32x16_bf16(kf0, qf[ks], sc[0], 0, 0, 0);
                    bf16x8 kf1 = *(const bf16x8*)&KsC[(32 + lo5) * 64 + (((2 * ks + hi) ^ rx) << 3)];
                    sc[1] = __builtin_amdgcn_mfma_f32_32x32x16_bf16(kf1, qf[ks], sc[1], 0, 0, 0);
                }

                const float SC2 = 0.18033688011112042f;  // 0.125 * log2(e)
                float mx = -1e30f;
                if (kv0 + 63 > q0w) {
                    #pragma unroll
                    for (int sub = 0; sub < 2; ++sub)
                        #pragma unroll
                        for (int r = 0; r < 16; ++r) {
                            int kvg = kv0 + 32 * sub + ((r & 3) + 8 * (r >> 2) + 4 * hi);
                            float v = sc[sub][r] * SC2;
                            v = (kvg > qg) ? -1e30f : v;
                            sc[sub][r] = v;
                            mx = fmaxf(mx, v);
                        }
                } else {
                    #pragma unroll
                    for (int sub = 0; sub < 2; ++sub)
                        #pragma unroll
                        for (int r = 0; r < 16; ++r) {
                            float v = sc[sub][r] * SC2;
                            sc[sub][r] = v;
                            mx = fmaxf(mx, v);
                        }
                }
                mx = fmaxf(mx, __shfl_xor(mx, 32));
                // T13 defer-max: only rescale when some lane's max grew > 8 (log2)
                if (__any(mx > m + 8.0f)) {
                    float mnew = fmaxf(m, mx);
                    float corr = exp2f(m - mnew);
                    m = mnew;
                    l *= corr;
                    #pragma unroll
                    for (int sub = 0; sub < 2; ++sub)
                        #pragma unroll
                        for (int r = 0; r < 16; ++r)
                            oacc[sub][r] *= corr;
                }
                float sum = 0.f;
                #pragma unroll
                for (int sub = 0; sub < 2; ++sub)
                    #pragma unroll
                    for (int r = 0; r < 16; ++r) {
                        float p = exp2f(sc[sub][r] - m);
                        sc[sub][r] = p;
                        sum += p;
                    }
                sum += __shfl_xor(sum, 32);
                l += sum;

                // repack P -> bf16 B-fragments via cvt_pk + permlane32_swap
                bf16x8 pb[4];
                #pragma unroll
                for (int sub = 0; sub < 2; ++sub) {
                    int a0 = cvtpk_bf16(sc[sub][0], sc[sub][1]);
                    int b0 = cvtpk_bf16(sc[sub][4], sc[sub][5]);
                    plswap(a0, b0);
                    int a1 = cvtpk_bf16(sc[sub][2], sc[sub][3]);
                    int b1 = cvtpk_bf16(sc[sub][6], sc[sub][7]);
                    plswap(a1, b1);
                    int4 w0; w0.x = a0; w0.y = a1; w0.z = b0; w0.w = b1;
                    pb[2 * sub] = *(bf16x8*)&w0;
                    int a2 = cvtpk_bf16(sc[sub][8], sc[sub][9]);
                    int b2 = cvtpk_bf16(sc[sub][12], sc[sub][13]);
                    plswap(a2, b2);
                    int a3 = cvtpk_bf16(sc[sub][10], sc[sub][11]);
                    int b3 = cvtpk_bf16(sc[sub][14], sc[sub][15]);
                    plswap(a3, b3);
                    int4 w1; w1.x = a2; w1.y = a3; w1.z = b2; w1.w = b3;
                    pb[2 * sub + 1] = *(bf16x8*)&w1;
                }

                // PV: O^T[dh][q] += mfma(A = V^T rows (dh), B = P^T cols (q))
                #pragma unroll
                for (int ks = 0; ks < 4; ++ks) {
                    bf16x8 vf0 = *(const bf16x8*)&VsC[lo5 * 64 + (((2 * ks + hi) ^ rx) << 3)];
                    oacc[0] = __builtin_amdgcn_mfma_f32_32x32x16_bf16(vf0, pb[ks], oacc[0], 0, 0, 0);
                    bf16x8 vf1 = *(const bf16x8*)&VsC[(32 + lo5) * 64 + (((2 * ks + hi) ^ rx) << 3)];
                    oacc[1] = __builtin_amdgcn_mfma_f32_32x32x16_bf16(vf1, pb[ks], oacc[1], 0, 0, 0);
                }
            }
            asm volatile("s_waitcnt vmcnt(0)" ::: "memory");
            __syncthreads();
            cur ^= 1;
        }

        // merge kpar partners via LDS (Vs region as f32 scratch)
        float* scr = (float*)&Vs[0][0][0];            // 2*64*33 floats
        float* mls = scr + 2 * 64 * 33;               // 2*64*2 floats
        int base = (qs * 64 + lane) * 33;
        if (kp == 1) {
            #pragma unroll
            for (int sub = 0; sub < 2; ++sub)
                #pragma unroll
                for (int i2 = 0; i2 < 16; ++i2)
                    scr[base + sub * 16 + i2] = oacc[sub][i2];
            mls[(qs * 64 + lane) * 2 + 0] = m;
            mls[(qs * 64 + lane) * 2 + 1] = l;
        }
        __syncthreads();
        if (kp == 0) {
            float m1 = mls[(qs * 64 + lane) * 2 + 0];
            float l1 = mls[(qs * 64 + lane) * 2 + 1];
            float mm = fmaxf(m, m1);
            float c0f = exp2f(m - mm), c1f = exp2f(m1 - mm);
            float inv = 1.0f / (l * c0f + l1 * c1f);
            c0f *= inv; c1f *= inv;
            ushort* cp = ctx + (size_t)(b * S + qg) * D + h * DH;
            #pragma unroll
            for (int sub = 0; sub < 2; ++sub)
                #pragma unroll
                for (int i2 = 0; i2 < 8; ++i2) {
                    int dh = ((2 * i2) & 3) + 8 * ((2 * i2) >> 2) + 4 * hi + 32 * sub;
                    float o0 = oacc[sub][2 * i2] * c0f + scr[base + sub * 16 + 2 * i2] * c1f;
                    float o1 = oacc[sub][2 * i2 + 1] * c0f + scr[base + sub * 16 + 2 * i2 + 1] * c1f;
                    *(int*)&cp[dh] = cvtpk_bf16(o0, o1);
                }
        }
        __syncthreads();   // scratch free before next half's staging
    }
}

extern "C" void kernel_launch(void* const* d_in, const int* in_sizes, int n_in,
                              void* d_out, int out_size, void* d_ws, size_t ws_size,
                              hipStream_t stream) {
    const float* X   = (const float*)d_in[0];
    const float* W_q = (const float*)d_in[1];
    const float* W_k = (const float*)d_in[2];
    const float* W_v = (const float*)d_in[3];
    const float* W_o = (const float*)d_in[4];
    const float* b_o = (const float*)d_in[5];
    float* out = (float*)d_out;

    ushort* Xb    = (ushort*)d_ws;                    // [4096][1024]
    ushort* Wqkvt = Xb    + (size_t)M_TOT * D;        // [3072][1024]
    ushort* Wot   = Wqkvt + (size_t)3 * D * D;        // [1024][1024]
    ushort* Qh    = Wot   + (size_t)D * D;            // [32][2048][64]
    ushort* Kh    = Qh    + (size_t)M_TOT * D;
    ushort* Vh    = Kh    + (size_t)M_TOT * D;
    ushort* Vtr   = Vh    + (size_t)M_TOT * D;        // [32][64][2048]
    ushort* Ctx   = Vtr   + (size_t)M_TOT * D;        // [4096][1024]

    k_convert<<<dim3(2048), dim3(256), 0, stream>>>(X, Xb, M_TOT * D / 4);
    k_transposeW<<<dim3(32, 32, 3), dim3(256), 0, stream>>>(W_q, W_k, W_v, Wqkvt);
    k_transposeW<<<dim3(32, 32, 1), dim3(256), 0, stream>>>(W_o, W_o, W_o, Wot);

    k_gemm<4><<<dim3(32, 24), dim3(256), 0, stream>>>(Xb, Wqkvt, Qh, Kh, Vh, nullptr, nullptr, 0);

    k_transposeV<<<dim3(64, 2, 32), dim3(256), 0, stream>>>(Vh, Vtr);

    k_attn<<<dim3(512), dim3(256), 0, stream>>>(Qh, Kh, Vtr, Ctx);

    k_gemm<2><<<dim3(64, 8), dim3(256), 0, stream>>>(Ctx, Wot, nullptr, nullptr, nullptr, out, b_o, 1);
}

// Round 4
// 131.088 us; speedup vs baseline: 1.7742x; 1.0249x over previous
//
#include <hip/hip_runtime.h>
#include <hip/hip_bf16.h>

#define S 2048
#define D 1024
#define NH 16
#define DH 64
#define M_TOT 4096  // B*S

typedef float f32x4 __attribute__((ext_vector_type(4)));
typedef float f32x16 __attribute__((ext_vector_type(16)));
typedef __bf16 bf16x8 __attribute__((ext_vector_type(8)));

static __device__ __forceinline__ ushort f2bf(float f) {
    unsigned u = __float_as_uint(f);
    u += 0x7fffu + ((u >> 16) & 1u);   // RNE
    return (ushort)(u >> 16);
}

static __device__ __forceinline__ int cvtpk_bf16(float lo, float hi) {
    int r;
    asm("v_cvt_pk_bf16_f32 %0, %1, %2" : "=v"(r) : "v"(lo), "v"(hi));
    return r;
}

static __device__ __forceinline__ void plswap(int& a, int& b) {
    asm("v_permlane32_swap_b32 %0, %1" : "+v"(a), "+v"(b));
}

static __device__ __forceinline__ void gload16(const ushort* g, ushort* l) {
    __builtin_amdgcn_global_load_lds(
        (const __attribute__((address_space(1))) void*)g,
        (__attribute__((address_space(3))) void*)l, 16, 0, 0);
}

// ---------------- elementwise f32 -> bf16 ----------------
__global__ void k_convert(const float* __restrict__ src, ushort* __restrict__ dst, int n4) {
    int i = blockIdx.x * blockDim.x + threadIdx.x;
    int stride = gridDim.x * blockDim.x;
    for (int idx = i; idx < n4; idx += stride) {
        float4 v = ((const float4*)src)[idx];
        ushort4 o;
        o.x = f2bf(v.x); o.y = f2bf(v.y); o.z = f2bf(v.z); o.w = f2bf(v.w);
        ((ushort4*)dst)[idx] = o;
    }
}

// ---------------- W [K][N] f32 -> Wt [zoff+N][K] bf16 (optional scale on z==0) ----
__global__ void k_transposeW(const float* __restrict__ w0, const float* __restrict__ w1,
                             const float* __restrict__ w2, ushort* __restrict__ dst,
                             float scale0) {
    __shared__ float tile[32][33];
    int z = blockIdx.z;
    const float* src = (z == 0) ? w0 : (z == 1) ? w1 : w2;
    float scl = (z == 0) ? scale0 : 1.0f;
    int zoff = z * 1024;
    int bn = blockIdx.x * 32;
    int bk = blockIdx.y * 32;
    int tx = threadIdx.x & 31, ty = threadIdx.x >> 5;
    #pragma unroll
    for (int i = 0; i < 32; i += 8)
        tile[ty + i][tx] = src[(size_t)(bk + ty + i) * D + bn + tx];
    __syncthreads();
    #pragma unroll
    for (int i = 0; i < 32; i += 8)
        dst[(size_t)(zoff + bn + ty + i) * D + bk + tx] = f2bf(tile[tx][ty + i] * scl);
}

// ---------------- V [BH][S][DH] -> Vt [BH][DH][S] (bf16) ----------------
__global__ void k_transposeV(const ushort* __restrict__ src, ushort* __restrict__ dst) {
    __shared__ ushort tile[32][33];
    int bh = blockIdx.z;
    const ushort* s = src + (size_t)bh * S * DH;
    ushort* d = dst + (size_t)bh * DH * S;
    int s0 = blockIdx.x * 32;
    int d0 = blockIdx.y * 32;
    int tx = threadIdx.x & 31, ty = threadIdx.x >> 5;
    #pragma unroll
    for (int i = 0; i < 32; i += 8)
        tile[ty + i][tx] = s[(size_t)(s0 + ty + i) * DH + d0 + tx];
    __syncthreads();
    #pragma unroll
    for (int i = 0; i < 32; i += 8)
        d[(size_t)(d0 + ty + i) * S + s0 + tx] = tile[tx][ty + i];
}

// ---------------- GEMM TN, m97-style: global_load_lds staging ----------------
template<int MF>
__global__ __launch_bounds__(256) void k_gemm(
    const ushort* __restrict__ A, const ushort* __restrict__ Bt,
    ushort* __restrict__ Qd, ushort* __restrict__ Kd, ushort* __restrict__ Vd,
    float* __restrict__ Od, const float* __restrict__ bias, int mode)
{
    constexpr int BM = MF * 32;
    __shared__ ushort As[BM * 32];
    __shared__ ushort Bs[128 * 32];
    int tid = threadIdx.x, wave = tid >> 6, lane = tid & 63;
    int wm = (wave >> 1) * (MF * 16), wn = (wave & 1) * 64;
    int bm = blockIdx.x * BM, bn0 = blockIdx.y * 128;
    int lr = lane & 15, lk = (lane >> 4) * 8;
    f32x4 acc[MF][4] = {};

    const ushort* Ap0 = A + (size_t)(bm + (tid >> 2)) * D + (tid & 3) * 8;
    const ushort* Ap1 = A + (size_t)(bm + ((tid + 256) >> 2)) * D + (tid & 3) * 8;
    const ushort* Bp0 = Bt + (size_t)(bn0 + (tid >> 2)) * D + (tid & 3) * 8;
    const ushort* Bp1 = Bt + (size_t)(bn0 + ((tid + 256) >> 2)) * D + (tid & 3) * 8;
    ushort* la0 = As + tid * 8;
    ushort* la1 = As + (tid + 256) * 8;
    ushort* lb0 = Bs + tid * 8;
    ushort* lb1 = Bs + (tid + 256) * 8;

    for (int k0 = 0; k0 < D; k0 += 32) {
        __syncthreads();
        gload16(Ap0, la0);
        if constexpr (MF == 4) gload16(Ap1, la1);
        gload16(Bp0, lb0);
        gload16(Bp1, lb1);
        Ap0 += 32; Bp0 += 32; Bp1 += 32;
        if constexpr (MF == 4) Ap1 += 32;
        asm volatile("s_waitcnt vmcnt(0)" ::: "memory");
        __syncthreads();
        bf16x8 af[MF], bfr[4];
        #pragma unroll
        for (int m = 0; m < MF; ++m) af[m] = *(const bf16x8*)&As[(wm + m * 16 + lr) * 32 + lk];
        #pragma unroll
        for (int n = 0; n < 4; ++n) bfr[n] = *(const bf16x8*)&Bs[(wn + n * 16 + lr) * 32 + lk];
        #pragma unroll
        for (int m = 0; m < MF; ++m)
            #pragma unroll
            for (int n = 0; n < 4; ++n)
                acc[m][n] = __builtin_amdgcn_mfma_f32_16x16x32_bf16(af[m], bfr[n], acc[m][n], 0, 0, 0);
    }

    int rr = (lane >> 4) * 4;
    if (mode == 0) {
        ushort* Dst = (blockIdx.y < 8) ? Qd : ((blockIdx.y < 16) ? Kd : Vd);
        int bnc = (blockIdx.y & 7) * 128;
        #pragma unroll
        for (int m = 0; m < MF; ++m) {
            #pragma unroll
            for (int n = 0; n < 4; ++n) {
                int gn = bnc + wn + n * 16 + lr;
                int h = gn >> 6, dd = gn & (DH - 1);
                #pragma unroll
                for (int r = 0; r < 4; ++r) {
                    int gm = bm + wm + m * 16 + rr + r;
                    int b = gm >> 11, ss = gm & (S - 1);
                    Dst[((size_t)(b * NH + h) * S + ss) * DH + dd] = f2bf(acc[m][n][r]);
                }
            }
        }
    } else {
        #pragma unroll
        for (int m = 0; m < MF; ++m) {
            #pragma unroll
            for (int n = 0; n < 4; ++n) {
                int gn = bn0 + wn + n * 16 + lr;
                float bv = bias[gn];
                #pragma unroll
                for (int r = 0; r < 4; ++r) {
                    int gm = bm + wm + m * 16 + rr + r;
                    Od[(size_t)gm * D + gn] = acc[m][n][r] + bv;
                }
            }
        }
    }
}

// ---------------- flash attention, causal ----------------
// 1024 blocks: one 64-row q-tile each, balanced (bh,qt) mapping.
// 4 waves = (qs: q-half, kp: kv-half of each 64-kv tile). 32KB LDS (dbuf K+V).
__global__ __launch_bounds__(256, 4) void k_attn(
    const ushort* __restrict__ Qh, const ushort* __restrict__ Kh,
    const ushort* __restrict__ Vt, ushort* __restrict__ ctx)
{
    __shared__ ushort Ks[2][4096];   // [dbuf][64 kv][64 dh], 16B-chunk XOR swizzled
    __shared__ ushort Vs[2][4096];   // [dbuf][64 dh][64 kv]

    int bid = blockIdx.x;
    int r_ = bid >> 8, c_ = bid & 255;
    int qt = (r_ & 1) ? (c_ >> 3) : 31 - (c_ >> 3);   // uniform per-CU work
    int bh = (c_ & 7) + 8 * r_;

    int tid = threadIdx.x;
    int wave = tid >> 6, lane = tid & 63;
    int lo5 = lane & 31, hi = lane >> 5;
    int qs = wave >> 1, kp = wave & 1;
    int rxl = lo5 & 7;
    int b = bh >> 4, h = bh & (NH - 1);

    const ushort* Qp = Qh + (size_t)bh * S * DH;
    const ushort* Kp = Kh + (size_t)bh * S * DH;
    const ushort* Vp = Vt + (size_t)bh * DH * S;

    int q0 = qt * 64, q0w = q0 + qs * 32, qg = q0w + lo5;
    int nt = qt + 1;

    bf16x8 qf[4];
    #pragma unroll
    for (int ks = 0; ks < 4; ++ks)
        qf[ks] = *(const bf16x8*)&Qp[(size_t)qg * DH + ks * 16 + hi * 8];

    // loop-invariant LDS read offsets (ushort units)
    int koff[4], vof[2];
    #pragma unroll
    for (int ks = 0; ks < 4; ++ks)
        koff[ks] = (kp * 32 + lo5) * 64 + (((2 * ks + hi) ^ rxl) << 3);
    #pragma unroll
    for (int kc = 0; kc < 2; ++kc)
        vof[kc] = lo5 * 64 + (((kp * 4 + 2 * kc + hi) ^ rxl) << 3);

    // loop-invariant staging pointers
    int p0 = tid, p1 = tid + 256;
    int kr0 = p0 >> 3, kc0 = ((p0 & 7) ^ (kr0 & 7)) << 3;
    int kr1 = p1 >> 3, kc1 = ((p1 & 7) ^ (kr1 & 7)) << 3;
    const ushort* gkA = Kp + (size_t)kr0 * DH + kc0;
    const ushort* gkB = Kp + (size_t)kr1 * DH + kc1;
    const ushort* gvA = Vp + (size_t)kr0 * S + kc0;
    const ushort* gvB = Vp + (size_t)kr1 * S + kc1;
    ushort* lk0 = &Ks[0][p0 * 8];
    ushort* lk1 = &Ks[0][p1 * 8];
    ushort* lv0 = &Vs[0][p0 * 8];
    ushort* lv1 = &Vs[0][p1 * 8];

    auto stage = [&](int t, int buf) {
        int ko = t * (64 * DH);
        int vo = t * 64;
        int lo = buf * 4096;
        gload16(gkA + ko, lk0 + lo);
        gload16(gkB + ko, lk1 + lo);
        gload16(gvA + vo, lv0 + lo);
        gload16(gvB + vo, lv1 + lo);
    };

    f32x16 oacc[2] = {};
    float m = -1e28f, l = 0.f;

    stage(0, 0);
    asm volatile("s_waitcnt vmcnt(0)" ::: "memory");
    __syncthreads();

    int cur = 0;
    #pragma unroll 1
    for (int t = 0; t < nt; ++t) {
        if (t + 1 < nt) stage(t + 1, cur ^ 1);
        bool fullmask = (t == qt) && (kp == 1) && (qs == 0);
        if (!fullmask) {
            const ushort* KsC = &Ks[cur][0];
            const ushort* VsC = &Vs[cur][0];
            f32x16 sc = (f32x16)(0.f);
            __builtin_amdgcn_s_setprio(1);
            #pragma unroll
            for (int ks = 0; ks < 4; ++ks) {
                bf16x8 kf = *(const bf16x8*)&KsC[koff[ks]];
                sc = __builtin_amdgcn_mfma_f32_32x32x16_bf16(kf, qf[ks], sc, 0, 0, 0);
            }
            __builtin_amdgcn_s_setprio(0);

            int kv0 = t * 64;
            float mx = -1e30f;
            if (t == qt && !(kp == 0 && qs == 1)) {
                #pragma unroll
                for (int r2 = 0; r2 < 16; ++r2) {
                    int kvg = kv0 + kp * 32 + ((r2 & 3) + 8 * (r2 >> 2) + 4 * hi);
                    float v = (kvg > qg) ? -1e30f : sc[r2];
                    sc[r2] = v;
                    mx = fmaxf(mx, v);
                }
            } else {
                #pragma unroll
                for (int r2 = 0; r2 < 16; ++r2) mx = fmaxf(mx, sc[r2]);
            }
            mx = fmaxf(mx, __shfl_xor(mx, 32));
            // T13 defer-max (log2 domain, THR=8)
            if (__any(mx > m + 8.0f)) {
                float mnew = fmaxf(m, mx);
                float corr = exp2f(m - mnew);
                m = mnew; l *= corr;
                #pragma unroll
                for (int sub = 0; sub < 2; ++sub)
                    #pragma unroll
                    for (int r2 = 0; r2 < 16; ++r2) oacc[sub][r2] *= corr;
            }
            float sum = 0.f;
            #pragma unroll
            for (int r2 = 0; r2 < 16; ++r2) {
                float p = exp2f(sc[r2] - m);
                sc[r2] = p;
                sum += p;
            }
            sum += __shfl_xor(sum, 32);
            l += sum;

            // repack P -> bf16 B-fragments via cvt_pk + permlane32_swap
            bf16x8 pb[2];
            {
                int a0 = cvtpk_bf16(sc[0], sc[1]);
                int b0 = cvtpk_bf16(sc[4], sc[5]);
                plswap(a0, b0);
                int a1 = cvtpk_bf16(sc[2], sc[3]);
                int b1 = cvtpk_bf16(sc[6], sc[7]);
                plswap(a1, b1);
                int4 w0; w0.x = a0; w0.y = a1; w0.z = b0; w0.w = b1;
                pb[0] = *(bf16x8*)&w0;
                int a2 = cvtpk_bf16(sc[8], sc[9]);
                int b2 = cvtpk_bf16(sc[12], sc[13]);
                plswap(a2, b2);
                int a3 = cvtpk_bf16(sc[10], sc[11]);
                int b3 = cvtpk_bf16(sc[14], sc[15]);
                plswap(a3, b3);
                int4 w1; w1.x = a2; w1.y = a3; w1.z = b2; w1.w = b3;
                pb[1] = *(bf16x8*)&w1;
            }

            __builtin_amdgcn_s_setprio(1);
            #pragma unroll
            for (int kc = 0; kc < 2; ++kc) {
                bf16x8 vf0 = *(const bf16x8*)&VsC[vof[kc]];
                oacc[0] = __builtin_amdgcn_mfma_f32_32x32x16_bf16(vf0, pb[kc], oacc[0], 0, 0, 0);
                bf16x8 vf1 = *(const bf16x8*)&VsC[vof[kc] + 32 * 64];
                oacc[1] = __builtin_amdgcn_mfma_f32_32x32x16_bf16(vf1, pb[kc], oacc[1], 0, 0, 0);
            }
            __builtin_amdgcn_s_setprio(0);
        }
        asm volatile("s_waitcnt vmcnt(0)" ::: "memory");
        __syncthreads();
        cur ^= 1;
    }

    // merge kp partners via LDS scratch (reuse Ks for O, Vs for m/l)
    float4* scr4 = (float4*)&Ks[0][0];   // 128 rows x 8 chunks x 16B = 16KB
    float2* mls = (float2*)&Vs[0][0];
    int row = qs * 64 + lane;
    if (kp == 1) {
        #pragma unroll
        for (int sub = 0; sub < 2; ++sub)
            #pragma unroll
            for (int cc = 0; cc < 4; ++cc) {
                float4 v4;
                v4.x = oacc[sub][4 * cc + 0];
                v4.y = oacc[sub][4 * cc + 1];
                v4.z = oacc[sub][4 * cc + 2];
                v4.w = oacc[sub][4 * cc + 3];
                scr4[row * 8 + ((sub * 4 + cc) ^ (row & 7))] = v4;
            }
        float2 ml; ml.x = m; ml.y = l;
        mls[row] = ml;
    }
    __syncthreads();
    if (kp == 0) {
        float2 ml1 = mls[row];
        float mm = fmaxf(m, ml1.x);
        float c0f = exp2f(m - mm), c1f = exp2f(ml1.x - mm);
        float inv = 1.0f / (l * c0f + ml1.y * c1f);
        c0f *= inv; c1f *= inv;
        ushort* cp = ctx + (size_t)(b * S + qg) * D + h * DH;
        #pragma unroll
        for (int sub = 0; sub < 2; ++sub) {
            #pragma unroll
            for (int cc = 0; cc < 4; ++cc) {
                float4 v4 = scr4[row * 8 + ((sub * 4 + cc) ^ (row & 7))];
                float o0 = oacc[sub][4 * cc + 0] * c0f + v4.x * c1f;
                float o1 = oacc[sub][4 * cc + 1] * c0f + v4.y * c1f;
                float o2 = oacc[sub][4 * cc + 2] * c0f + v4.z * c1f;
                float o3 = oacc[sub][4 * cc + 3] * c0f + v4.w * c1f;
                int dh = 8 * cc + 4 * hi + 32 * sub;
                int2 w2; w2.x = cvtpk_bf16(o0, o1); w2.y = cvtpk_bf16(o2, o3);
                *(int2*)&cp[dh] = w2;
            }
        }
    }
}

extern "C" void kernel_launch(void* const* d_in, const int* in_sizes, int n_in,
                              void* d_out, int out_size, void* d_ws, size_t ws_size,
                              hipStream_t stream) {
    const float* X   = (const float*)d_in[0];
    const float* W_q = (const float*)d_in[1];
    const float* W_k = (const float*)d_in[2];
    const float* W_v = (const float*)d_in[3];
    const float* W_o = (const float*)d_in[4];
    const float* b_o = (const float*)d_in[5];
    float* out = (float*)d_out;

    ushort* Xb    = (ushort*)d_ws;
    ushort* Wqkvt = Xb    + (size_t)M_TOT * D;
    ushort* Wot   = Wqkvt + (size_t)3 * D * D;
    ushort* Qh    = Wot   + (size_t)D * D;
    ushort* Kh    = Qh    + (size_t)M_TOT * D;
    ushort* Vh    = Kh    + (size_t)M_TOT * D;
    ushort* Vtr   = Vh    + (size_t)M_TOT * D;
    ushort* Ctx   = Vtr   + (size_t)M_TOT * D;

    k_convert<<<dim3(2048), dim3(256), 0, stream>>>(X, Xb, M_TOT * D / 4);
    // fold softmax scale (1/8 * log2(e)) into W_q
    k_transposeW<<<dim3(32, 32, 3), dim3(256), 0, stream>>>(W_q, W_k, W_v, Wqkvt, 0.18033688011112042f);
    k_transposeW<<<dim3(32, 32, 1), dim3(256), 0, stream>>>(W_o, W_o, W_o, Wot, 1.0f);

    k_gemm<4><<<dim3(32, 24), dim3(256), 0, stream>>>(Xb, Wqkvt, Qh, Kh, Vh, nullptr, nullptr, 0);

    k_transposeV<<<dim3(64, 2, 32), dim3(256), 0, stream>>>(Vh, Vtr);

    k_attn<<<dim3(1024), dim3(256), 0, stream>>>(Qh, Kh, Vtr, Ctx);

    k_gemm<2><<<dim3(64, 8), dim3(256), 0, stream>>>(Ctx, Wot, nullptr, nullptr, nullptr, out, b_o, 1);
}